// Round 4
// baseline (502.221 us; speedup 1.0000x reference)
//
#include <hip/hip_runtime.h>
#include <stdint.h>

typedef uint64_t u64;
typedef uint32_t u32;

#define NB    8
#define NQ    4096
#define NKEY  4096
#define HD    64
#define CV    64
#define KSEL  16
#define NWAVE 8
#define KPP   (NKEY / NWAVE)   /* 512 keys per partition-wave */
#define QPB   64               /* queries per block (= lanes) */
#define BLK   (NWAVE * 64)     /* 512 threads */
#define NBIN  32
#define NBINP 33               /* padded row: (q*33+b)%32 spreads banks */
#define CMAX  64               /* candidate slots per query */
#define CROW  (CMAX + 1)       /* padded u64 row */

/* padding entry: d2=+inf, idx=max  (fp32 bits of nonneg floats are monotone as u32) */
#define PADV ((((u64)0x7F800000u) << 32) | (u64)0xFFFFFFFFu)

/* fully-unrolled bitonic sort-16, ascending (static indices only) */
__device__ __forceinline__ void sort16(u64 v[KSEL]) {
#pragma unroll
    for (int k = 2; k <= KSEL; k <<= 1) {
#pragma unroll
        for (int j = k >> 1; j > 0; j >>= 1) {
#pragma unroll
            for (int i = 0; i < KSEL; i++) {
                const int l = i ^ j;
                if (l > i) {
                    const bool up = ((i & k) == 0);
                    const u64 a = v[i], b = v[l];
                    const bool sw = up ? (a > b) : (a < b);
                    v[i] = sw ? b : a;
                    v[l] = sw ? a : b;
                }
            }
        }
    }
}

extern "C" __global__ void __launch_bounds__(BLK, 4)
sparse_bev_attn_kernel(const float* __restrict__ qg,
                       const float* __restrict__ kg,
                       const float* __restrict__ vg,
                       const float* __restrict__ qw,
                       const float* __restrict__ qbias,
                       const float* __restrict__ kw,
                       const float* __restrict__ kbias,
                       float* __restrict__ outg)
{
    __shared__ u32   hist[QPB][NBINP];   /* 8448 B; dead after thr -> sidx/sw overlay */
    __shared__ u64   cand[QPB][CROW];    /* 33280 B */
    __shared__ u32   ccnt[QPB];
    __shared__ float thrf[QPB];
    u32*   sidx = &hist[0][0];                    /* [QPB][KSEL] u32 = 4096 B */
    float* sw_  = (float*)(&hist[0][0] + QPB * KSEL);

    const int tid  = threadIdx.x;
    const int wv   = tid >> 6;                    /* key partition */
    const int lane = tid & 63;                    /* query within block */
    const int b    = blockIdx.x >> 6;
    const int q0   = (blockIdx.x & 63) << 6;
    const int qi   = q0 + lane;

    const float2* kp = (const float2*)(kg + (size_t)b * NKEY * 2);
    const float2  qc = *(const float2*)(qg + ((size_t)b * NQ + qi) * 2);
    const float qx = qc.x, qy = qc.y;

    for (int i = tid; i < QPB * NBINP; i += BLK) (&hist[0][0])[i] = 0u;
    if (tid < QPB) ccnt[tid] = 0u;
    __syncthreads();

    const int jb = __builtin_amdgcn_readfirstlane(wv * KPP);
    const float2* kpart = kp + jb;                /* uniform base -> scalar loads */

    /* bin = clamp(exp(d2) - 107, 0, 31): bin b covers d2 in [2^(b-20), 2^(b-19)) */
    auto binof = [](float d2) -> int {
        const int t = (int)(__float_as_uint(d2) >> 23) - 107;
        return t < 0 ? 0 : (t > NBIN - 1 ? NBIN - 1 : t);
    };

    /* ---- pass A: per-query exponent histogram of all 4096 d2 ---- */
    {
        u32* hrow = &hist[lane][0];
        for (int i0 = 0; i0 < KPP; i0 += 16) {
            const float4* p4 = (const float4*)(kpart + i0);
#pragma unroll
            for (int u = 0; u < 8; u++) {
                const float4 kk = p4[u];
                const float dx0 = qx - kk.x, dy0 = qy - kk.y;
                const float dx1 = qx - kk.z, dy1 = qy - kk.w;
                const float d20 = fmaf(dx0, dx0, dy0 * dy0);
                const float d21 = fmaf(dx1, dx1, dy1 * dy1);
                atomicAdd(&hrow[binof(d20)], 1u);
                atomicAdd(&hrow[binof(d21)], 1u);
            }
        }
    }
    __syncthreads();

    /* ---- threshold: first bin with cumsum >= 16; thr = bin upper edge ---- */
    if (tid < QPB) {
        u32 cum = 0;
        int bsel = NBIN - 1;
#pragma unroll
        for (int bb = 0; bb < NBIN; bb++) {
            const u32 nc = cum + hist[tid][bb];
            bsel = (cum < KSEL && nc >= KSEL) ? bb : bsel;
            cum = nc;
        }
        thrf[tid] = __uint_as_float((u32)(108 + bsel) << 23);
    }
    __syncthreads();

    /* ---- pass B: collect ALL keys with d2 <= thr (superset of exact top-16) ---- */
    {
        const float thr = thrf[lane];
        for (int i0 = 0; i0 < KPP; i0 += 16) {
            const float4* p4 = (const float4*)(kpart + i0);
#pragma unroll
            for (int u = 0; u < 8; u++) {
                const float4 kk = p4[u];
                const float dx0 = qx - kk.x, dy0 = qy - kk.y;
                const float dx1 = qx - kk.z, dy1 = qy - kk.w;
                const float d20 = fmaf(dx0, dx0, dy0 * dy0);
                const float d21 = fmaf(dx1, dx1, dy1 * dy1);
                if (d20 <= thr) {
                    const u32 pos = atomicAdd(&ccnt[lane], 1u);
                    if (pos < CMAX)
                        cand[lane][pos] = (((u64)__float_as_uint(d20)) << 32) | (u32)(jb + i0 + 2 * u);
                }
                if (d21 <= thr) {
                    const u32 pos = atomicAdd(&ccnt[lane], 1u);
                    if (pos < CMAX)
                        cand[lane][pos] = (((u64)__float_as_uint(d21)) << 32) | (u32)(jb + i0 + 2 * u + 1);
                }
            }
        }
    }
    __syncthreads();

    /* ---- overflow fallback (prob ~0): exact serial top-16 for that query ---- */
    if (tid < QPB && ccnt[tid] > CMAX) {
        u64 bst[KSEL];
#pragma unroll
        for (int s = 0; s < KSEL; s++) bst[s] = PADV;
        for (int j = 0; j < NKEY; j++) {
            const float2 kc = kp[j];
            const float dx = qx - kc.x, dy = qy - kc.y;
            const float d2 = fmaf(dx, dx, dy * dy);
            const u64 pk = (((u64)__float_as_uint(d2)) << 32) | (u32)j;
            if (pk < bst[KSEL - 1]) {
#pragma unroll
                for (int s = KSEL - 1; s >= 1; s--) {
                    const u64 a = bst[s - 1], c = bst[s];
                    bst[s] = (pk < a) ? a : (pk < c ? pk : c);
                }
                bst[0] = pk < bst[0] ? pk : bst[0];
            }
        }
#pragma unroll
        for (int s = 0; s < KSEL; s++) cand[tid][s] = bst[s];
        ccnt[tid] = KSEL;
    }
    __syncthreads();

    /* ---- quarter sort: waves 0-3, lane q sorts cand[q][16w..16w+15] ---- */
    if (wv < 4) {
        const int q = lane;
        const int n = (int)min(ccnt[q], (u32)CMAX);
        u64 t[KSEL];
#pragma unroll
        for (int s = 0; s < KSEL; s++) {
            const int si = wv * KSEL + s;
            t[s] = (si < n) ? cand[q][si] : PADV;
        }
        sort16(t);
#pragma unroll
        for (int s = 0; s < KSEL; s++) cand[q][wv * KSEL + s] = t[s];
    }
    __syncthreads();

    /* ---- wave 0: 4-way merge -> top-16; affine scores; softmax ---- */
    if (tid < QPB) {
        /* 9 query-independent sums via 64-lane butterfly (h = tid) */
        const float2 a = ((const float2*)qw)[tid];
        const float2 c = ((const float2*)kw)[tid];
        const float qbh = qbias[tid], kbh = kbias[tid];
        float s1 = a.x * c.x, s2 = a.y * c.x, s3 = qbh * c.x;
        float s4 = a.x * c.y, s5 = a.y * c.y, s6 = qbh * c.y;
        float s7 = a.x * kbh, s8 = a.y * kbh, s9 = qbh * kbh;
#pragma unroll
        for (int off = 32; off; off >>= 1) {
            s1 += __shfl_xor(s1, off); s2 += __shfl_xor(s2, off); s3 += __shfl_xor(s3, off);
            s4 += __shfl_xor(s4, off); s5 += __shfl_xor(s5, off); s6 += __shfl_xor(s6, off);
            s7 += __shfl_xor(s7, off); s8 += __shfl_xor(s8, off); s9 += __shfl_xor(s9, off);
        }
        const float A  = fmaf(qx, s1, fmaf(qy, s2, s3));
        const float Bb = fmaf(qx, s4, fmaf(qy, s5, s6));
        const float Cc = fmaf(qx, s7, fmaf(qy, s8, s9));

        /* 4-way sorted merge, first 16 by (d2, idx) */
        const int t = tid;
        u64 msel[KSEL];
        int p0 = 0, p1 = 0, p2 = 0, p3 = 0;
#pragma unroll
        for (int s = 0; s < KSEL; s++) {
            const u64 v0 = cand[t][p0];
            const u64 v1 = cand[t][KSEL + p1];
            const u64 v2 = cand[t][2 * KSEL + p2];
            const u64 v3 = cand[t][3 * KSEL + p3];
            const u64 m01 = v0 < v1 ? v0 : v1;
            const u64 m23 = v2 < v3 ? v2 : v3;
            const u64 m   = m01 < m23 ? m01 : m23;
            p0 += (m == v0); p1 += (m == v1); p2 += (m == v2); p3 += (m == v3);
            /* clamp pointers to 15 (PAD-safe: merged lists each hold <=16) */
            p0 = p0 > KSEL - 1 ? KSEL - 1 : p0;
            p1 = p1 > KSEL - 1 ? KSEL - 1 : p1;
            p2 = p2 > KSEL - 1 ? KSEL - 1 : p2;
            p3 = p3 > KSEL - 1 ? KSEL - 1 : p3;
            msel[s] = m;
        }

        float sc[KSEL];
        float mx = -__builtin_inff();
#pragma unroll
        for (int s = 0; s < KSEL; s++) {
            const float2 kc = kp[(u32)msel[s]];
            sc[s] = fmaf(A, kc.x, fmaf(Bb, kc.y, Cc));
            mx = fmaxf(mx, sc[s]);
        }
        float sum = 0.f;
#pragma unroll
        for (int s = 0; s < KSEL; s++) { sc[s] = expf(sc[s] - mx); sum += sc[s]; }
        const float inv = 1.f / sum;
#pragma unroll
        for (int s = 0; s < KSEL; s++) {
            sidx[t * KSEL + s] = (u32)msel[s];    /* overlay on dead hist region */
            sw_ [t * KSEL + s] = sc[s] * inv;
        }
    }
    __syncthreads();

    /* ---- phase 3: weighted V gather (lane = channel, coalesced 256B rows) ---- */
    const float* vb = vg + (size_t)b * NKEY * CV;
    float* ob = outg + ((size_t)b * NQ + q0) * CV;
    for (int qq = wv; qq < QPB; qq += NWAVE) {
        float acc = 0.f;
#pragma unroll
        for (int s = 0; s < KSEL; s++) {
            const u32 id   = sidx[qq * KSEL + s]; /* wave-uniform LDS read */
            const float wg = sw_[qq * KSEL + s];
            acc = fmaf(wg, vb[(size_t)id * CV + lane], acc);
        }
        ob[qq * CV + lane] = acc;
    }
}

extern "C" void kernel_launch(void* const* d_in, const int* in_sizes, int n_in,
                              void* d_out, int out_size, void* d_ws, size_t ws_size,
                              hipStream_t stream) {
    const float* q  = (const float*)d_in[0];
    const float* k  = (const float*)d_in[1];
    const float* v  = (const float*)d_in[2];
    const float* qw = (const float*)d_in[3];
    const float* qb = (const float*)d_in[4];
    const float* kw = (const float*)d_in[5];
    const float* kb = (const float*)d_in[6];
    /* d_in[7] = top_k (always 16; K is compile-time) */
    float* out = (float*)d_out;

    dim3 grid(NB * (NQ / QPB));   /* 512 blocks */
    dim3 block(BLK);              /* 512 threads = 8 waves */
    hipLaunchKernelGGL(sparse_bev_attn_kernel, grid, block, 0, stream,
                       q, k, v, qw, qb, kw, kb, out);
}

// Round 5
// 74.938 us; speedup vs baseline: 6.7018x; 6.7018x over previous
//
#include <hip/hip_runtime.h>
#include <stdint.h>

typedef uint64_t u64;
typedef uint32_t u32;

#define NB    8
#define NQ    4096
#define NKEY  4096
#define CV    64
#define KSEL  16
#define NWAVE 8              /* waves per block; 1 query per wave */
#define BLK   (NWAVE * 64)   /* 512 threads */
#define CMAX  64             /* candidate slots per wave */

/* pad: d2=+inf, idx=max (fp32 bits of nonneg floats are order-monotone as u32) */
#define PADV ((((u64)0x7F800000u) << 32) | (u64)0xFFFFFFFFu)

__device__ __forceinline__ u64 shflxor_u64(u64 v, int m) {
    const u32 lo = __shfl_xor((int)(u32)v, m);
    const u32 hi = __shfl_xor((int)(u32)(v >> 32), m);
    return (((u64)hi) << 32) | lo;
}

/* across-lane bitonic sort (64 lanes), ascending */
__device__ __forceinline__ float lanesort64_f32(float v, int lane) {
#pragma unroll
    for (int k = 2; k <= 64; k <<= 1) {
#pragma unroll
        for (int j = k >> 1; j > 0; j >>= 1) {
            const float p = __shfl_xor(v, j);
            const bool up    = ((lane & k) == 0);
            const bool lower = ((lane & j) == 0);
            v = (lower == up) ? fminf(v, p) : fmaxf(v, p);
        }
    }
    return v;
}

__device__ __forceinline__ u64 lanesort64_u64(u64 v, int lane) {
#pragma unroll
    for (int k = 2; k <= 64; k <<= 1) {
#pragma unroll
        for (int j = k >> 1; j > 0; j >>= 1) {
            const u64 p = shflxor_u64(v, j);
            const bool up    = ((lane & k) == 0);
            const bool lower = ((lane & j) == 0);
            const u64 mn = v < p ? v : p;
            const u64 mx = v < p ? p : v;
            v = (lower == up) ? mn : mx;
        }
    }
    return v;
}

/* ---- setup: 9 query-independent affine sums over H=64 -> d_ws ---- */
extern "C" __global__ void setup_sums_kernel(const float* __restrict__ qw,
                                             const float* __restrict__ qb,
                                             const float* __restrict__ kw,
                                             const float* __restrict__ kb,
                                             float* __restrict__ w9) {
    const int h = threadIdx.x & 63;
    const float2 a = ((const float2*)qw)[h];
    const float2 c = ((const float2*)kw)[h];
    const float qbh = qb[h], kbh = kb[h];
    float s[9] = { a.x * c.x, a.y * c.x, qbh * c.x,
                   a.x * c.y, a.y * c.y, qbh * c.y,
                   a.x * kbh, a.y * kbh, qbh * kbh };
#pragma unroll
    for (int i = 0; i < 9; ++i)
#pragma unroll
        for (int off = 32; off; off >>= 1) s[i] += __shfl_xor(s[i], off);
    if (h == 0) {
#pragma unroll
        for (int i = 0; i < 9; ++i) w9[i] = s[i];
    }
}

extern "C" __global__ void __launch_bounds__(BLK, 2)
sparse_bev_attn_kernel(const float* __restrict__ qg,
                       const float* __restrict__ kg,
                       const float* __restrict__ vg,
                       const float* __restrict__ sums9,
                       float* __restrict__ outg)
{
    __shared__ u64 cand[NWAVE][CMAX];         /* 4 KB; per-wave private, no barriers */

    const int tid  = threadIdx.x;
    const int wv   = tid >> 6;
    const int lane = tid & 63;
    const int b    = blockIdx.x >> 9;                 /* 512 blocks per batch */
    const int qi   = ((blockIdx.x & 511) << 3) + wv;  /* 1 query per wave */

    const float2* kp = (const float2*)(kg + (size_t)b * NKEY * 2);
    const float2  qc = ((const float2*)qg)[(size_t)b * NQ + qi];
    const float qx = qc.x, qy = qc.y;

    /* ---- scan: all 4096 d2 in regs (64/lane, static idx), fold lane-min ---- */
    const float4* kp4 = (const float4*)kp;            /* lane holds keys c*128+2*lane(+1) */
    float d2r[64];
    float mn = __builtin_inff();
#pragma unroll
    for (int c = 0; c < 32; ++c) {
        const float4 kk = kp4[c * 64 + lane];
        const float dx0 = qx - kk.x, dy0 = qy - kk.y;
        const float dx1 = qx - kk.z, dy1 = qy - kk.w;
        d2r[2 * c]     = fmaf(dx0, dx0, dy0 * dy0);
        d2r[2 * c + 1] = fmaf(dx1, dx1, dy1 * dy1);
        mn = fminf(mn, fminf(d2r[2 * c], d2r[2 * c + 1]));
    }

    /* ---- threshold: 16th-smallest lane-min (distribution-free, E[cnt]~18) ---- */
    const float thr = __shfl(lanesort64_f32(mn, lane), 15);

    /* ---- collect all d2 <= t via ballot-compacted LDS append ---- */
    const u32 l2 = (u32)(lane << 1);
    auto collect = [&](float t) -> int {
        int c = 0;
#pragma unroll
        for (int r = 0; r < 64; ++r) {
            const bool acc = d2r[r] <= t;
            const u64 mask = __ballot(acc);
            if (mask) {                               /* uniform branch, usually false */
                const int pos = c + (int)__builtin_amdgcn_mbcnt_hi(
                    (u32)(mask >> 32), __builtin_amdgcn_mbcnt_lo((u32)mask, 0));
                if (acc && pos < CMAX) {
                    const u32 kidx = (u32)(((r >> 1) << 7) + (r & 1)) + l2;
                    cand[wv][pos] = (((u64)__float_as_uint(d2r[r])) << 32) | kidx;
                }
                c += __popcll(mask);
            }
        }
        return c;
    };

    int cnt = collect(thr);
    if (cnt > CMAX) {                                 /* ~never: exact-threshold fallback */
        u32 lo = 0, hi = 0x7F800000u;
        while (lo < hi) {
            const u32 mid = (lo + hi) >> 1;
            const float t = __uint_as_float(mid);
            int c = 0;
#pragma unroll
            for (int r = 0; r < 64; ++r) c += (d2r[r] <= t) ? 1 : 0;
#pragma unroll
            for (int off = 32; off; off >>= 1) c += __shfl_xor(c, off);
            if (c >= KSEL) hi = mid; else lo = mid + 1;
        }
        cnt = collect(__uint_as_float(lo));
        if (cnt > CMAX) cnt = CMAX;                   /* tie-flood: impossible data */
    }

    /* ---- exact top-16 by (d2, idx): 64-lane sort, lanes 0..15 win ---- */
    u64 myv = (lane < cnt) ? cand[wv][lane] : PADV;
    myv = lanesort64_u64(myv, lane);
    const u32 myidx = (u32)myv;

    /* ---- affine scores + width-16 softmax ---- */
    const float s1 = sums9[0], s2 = sums9[1], s3 = sums9[2];
    const float s4 = sums9[3], s5 = sums9[4], s6 = sums9[5];
    const float s7 = sums9[6], s8 = sums9[7], s9 = sums9[8];
    const float A  = fmaf(qx, s1, fmaf(qy, s2, s3));
    const float Bb = fmaf(qx, s4, fmaf(qy, s5, s6));
    const float Cc = fmaf(qx, s7, fmaf(qy, s8, s9));

    const int sel = (lane < KSEL) ? (int)myidx : 0;
    const float2 kc = kp[sel];
    const float score = fmaf(A, kc.x, fmaf(Bb, kc.y, Cc));
    float mx = score;
#pragma unroll
    for (int off = 8; off; off >>= 1) mx = fmaxf(mx, __shfl_xor(mx, off));
    const float e = __expf(score - mx);
    float sum = e;
#pragma unroll
    for (int off = 8; off; off >>= 1) sum += __shfl_xor(sum, off);
    const float w = e / sum;                          /* valid in lanes 0..15 */

    /* ---- V gather: readlane-broadcast (scalar base), lane = channel ---- */
    const float* vb = vg + (size_t)b * NKEY * CV;
    float acc = 0.f;
#pragma unroll
    for (int s = 0; s < KSEL; ++s) {
        const u32 id   = (u32)__builtin_amdgcn_readlane((int)myidx, s);
        const float ws = __uint_as_float(
            (u32)__builtin_amdgcn_readlane((int)__float_as_uint(w), s));
        acc = fmaf(ws, vb[(size_t)id * CV + lane], acc);
    }
    outg[((size_t)b * NQ + qi) * CV + lane] = acc;
}

extern "C" void kernel_launch(void* const* d_in, const int* in_sizes, int n_in,
                              void* d_out, int out_size, void* d_ws, size_t ws_size,
                              hipStream_t stream) {
    const float* q  = (const float*)d_in[0];
    const float* k  = (const float*)d_in[1];
    const float* v  = (const float*)d_in[2];
    const float* qw = (const float*)d_in[3];
    const float* qb = (const float*)d_in[4];
    const float* kw = (const float*)d_in[5];
    const float* kb = (const float*)d_in[6];
    /* d_in[7] = top_k (always 16; compile-time) */
    float* out = (float*)d_out;
    float* w9  = (float*)d_ws;

    hipLaunchKernelGGL(setup_sums_kernel, dim3(1), dim3(64), 0, stream,
                       qw, qb, kw, kb, w9);
    hipLaunchKernelGGL(sparse_bev_attn_kernel, dim3(NB * (NQ / NWAVE)), dim3(BLK),
                       0, stream, q, k, v, w9, out);
}